// Round 7
// baseline (704.857 us; speedup 1.0000x reference)
//
#include <hip/hip_runtime.h>

#define N_NODES 100000
#define N_EDGES 3200000
#define IN_DIM 20
#define HIDDEN 4096
#define OUT_DIM 2
#define BN_EPS 1e-5f

#define NB 1000        // buckets
#define NPB 100        // nodes per bucket
#define BIN_CHUNK 8192
#define BIN_NWG ((N_EDGES + BIN_CHUNK - 1) / BIN_CHUNK)  // 391

// ================= workspace layout (byte offsets) =================
// deg   : int [100000]    @ 0          (400000)
// dinv  : float[100000]   @ 400000     (400000)
// agg   : float[2000000]  @ 800000     (8000000)
// bh    : int [1000]      @ 8800000    (4000)
// bo    : int [1001]      @ 8804000    (4004)
// gcur  : int [1000]      @ 8808004    (4000)
// stats : S1[20] S2[400] mean[20] cov[400] a0c[20] W2[40] dvec[2]
//         @ 8812004 (3608 B contiguous, memset once)
// rec   : int2[3200000]   @ 8815616    (25600000)  [8-aligned]
#define WS_NEED 34415616ull

__global__ void k_deg(const int* __restrict__ ei, int* __restrict__ deg) {
    int e = blockIdx.x * blockDim.x + threadIdx.x;
    if (e < N_EDGES) atomicAdd(&deg[ei[N_EDGES + e]], 1);
}

__global__ void k_dinv(const int* __restrict__ deg, float* __restrict__ dinv) {
    int i = blockIdx.x * blockDim.x + threadIdx.x;
    if (i < N_NODES) dinv[i] = rsqrtf((float)(deg[i] + 1));  // +1 self loop
}

// bh[b] = sum of deg over the bucket's 100 nodes (= record count per bucket)
__global__ void k_bh(const int* __restrict__ deg, int* __restrict__ bh) {
    __shared__ int lds[128];
    int b = blockIdx.x, t = threadIdx.x;
    int v = (t < NPB) ? deg[b * NPB + t] : 0;
    lds[t] = v;
    __syncthreads();
    for (int off = 64; off > 0; off >>= 1) {
        if (t < off) lds[t] += lds[t + off];
        __syncthreads();
    }
    if (t == 0) bh[b] = lds[0];
}

// exclusive scan of bh[1000] -> bo[1001]; also seed gcur
__global__ void k_scan_bo(const int* __restrict__ bh, int* __restrict__ bo,
                          int* __restrict__ gcur) {
    __shared__ int lds[256];
    int t = threadIdx.x;
    int base = t * 4;
    int v0 = (base + 0 < NB) ? bh[base + 0] : 0;
    int v1 = (base + 1 < NB) ? bh[base + 1] : 0;
    int v2 = (base + 2 < NB) ? bh[base + 2] : 0;
    int v3 = (base + 3 < NB) ? bh[base + 3] : 0;
    int tsum = v0 + v1 + v2 + v3;
    int x = tsum;
    lds[t] = x;
    __syncthreads();
    for (int off = 1; off < 256; off <<= 1) {
        int y = (t >= off) ? lds[t - off] : 0;
        __syncthreads();
        x += y;
        lds[t] = x;
        __syncthreads();
    }
    int ex = x - tsum;
    if (base + 0 < NB) { bo[base + 0] = ex;                 gcur[base + 0] = ex; }
    if (base + 1 < NB) { bo[base + 1] = ex + v0;            gcur[base + 1] = ex + v0; }
    if (base + 2 < NB) { bo[base + 2] = ex + v0 + v1;       gcur[base + 2] = ex + v0 + v1; }
    if (base + 3 < NB) { bo[base + 3] = ex + v0 + v1 + v2;  gcur[base + 3] = ex + v0 + v1 + v2; }
    if (t == 255) bo[NB] = x;  // = N_EDGES
}

// bin edges into bucket-contiguous record lists; per-WG LDS hist + range
// reservation => writes land in ~64B sequential runs, not broken lines.
__global__ void k_bin(const int* __restrict__ ei, int* __restrict__ gcur,
                      int2* __restrict__ rec) {
    __shared__ int lh[NB];
    __shared__ int loff[NB];
    int t = threadIdx.x;
    int ebase = blockIdx.x * BIN_CHUNK;
    int eend = min(ebase + BIN_CHUNK, N_EDGES);
    for (int b = t; b < NB; b += 256) lh[b] = 0;
    __syncthreads();
    for (int e = ebase + t; e < eend; e += 256) {
        int c = ei[N_EDGES + e];
        atomicAdd(&lh[c / NPB], 1);
    }
    __syncthreads();
    for (int b = t; b < NB; b += 256) {
        int cnt = lh[b];
        loff[b] = cnt ? atomicAdd(&gcur[b], cnt) : 0;
        lh[b] = 0;  // reuse as local cursor
    }
    __syncthreads();
    for (int e = ebase + t; e < eend; e += 256) {
        int r = ei[e];
        int c = ei[N_EDGES + e];
        int b = c / NPB;
        int p = loff[b] + atomicAdd(&lh[b], 1);
        rec[p] = make_int2(r, c);
    }
}

// one WG per bucket: LDS tile[100][20] init with self-loop term, LDS-atomic
// accumulate records, stream tile to agg. No global atomics.
__global__ void k_agg(const int2* __restrict__ rec, const int* __restrict__ bo,
                      const float* __restrict__ nf, const float* __restrict__ dinv,
                      float* __restrict__ agg) {
    __shared__ float tile[NPB * IN_DIM];  // 8000 B
    __shared__ float sdinv[NPB];
    int b = blockIdx.x;
    int t = threadIdx.x;
    int base = b * NPB;
    if (t < NPB) sdinv[t] = dinv[base + t];
    __syncthreads();
    const float4* nf4 = (const float4*)nf;
    float4* tile4 = (float4*)tile;
    for (int idx = t; idx < NPB * IN_DIM / 4; idx += 256) {  // 500
        int j = idx / 5;
        float d = sdinv[j];
        float s = d * d;
        float4 v = nf4[base * 5 + idx];
        v.x *= s; v.y *= s; v.z *= s; v.w *= s;
        tile4[idx] = v;
    }
    __syncthreads();
    int rend = bo[b + 1];
    for (int i = bo[b] + t; i < rend; i += 256) {
        int2 rc = rec[i];
        int r = rc.x;
        int cl = rc.y - base;
        float w = dinv[r] * sdinv[cl];
        const float4* nfr = nf4 + r * 5;
        float* dst = tile + cl * IN_DIM;
#pragma unroll
        for (int g = 0; g < 5; g++) {
            float4 v = nfr[g];
            atomicAdd(&dst[g * 4 + 0], v.x * w);
            atomicAdd(&dst[g * 4 + 1], v.y * w);
            atomicAdd(&dst[g * 4 + 2], v.z * w);
            atomicAdd(&dst[g * 4 + 3], v.w * w);
        }
    }
    __syncthreads();
    float4* agg4 = (float4*)agg;
    for (int idx = t; idx < NPB * IN_DIM / 4; idx += 256)
        agg4[base * 5 + idx] = tile4[idx];
}

// moments, 3 rows per block-y: y in [0,7); row index 20 == "ones" (-> S1)
__global__ void k_moments3(const float* __restrict__ agg, float* __restrict__ S1,
                           float* __restrict__ S2) {
    int y = blockIdx.y;
    int a0 = 3 * y, a1 = 3 * y + 1, a2 = 3 * y + 2;
    float acc0[IN_DIM], acc1[IN_DIM], acc2[IN_DIM];
#pragma unroll
    for (int b = 0; b < IN_DIM; b++) { acc0[b] = 0.f; acc1[b] = 0.f; acc2[b] = 0.f; }
    int stride = gridDim.x * blockDim.x;
    for (int i = blockIdx.x * blockDim.x + threadIdx.x; i < N_NODES; i += stride) {
        const float* row = agg + i * IN_DIM;
        float v[IN_DIM];
#pragma unroll
        for (int b = 0; b < IN_DIM; b++) v[b] = row[b];
        float va0 = row[a0];
        float va1 = row[a1];
        float va2 = (a2 < IN_DIM) ? row[a2] : 1.0f;
#pragma unroll
        for (int b = 0; b < IN_DIM; b++) {
            acc0[b] += va0 * v[b];
            acc1[b] += va1 * v[b];
            acc2[b] += va2 * v[b];
        }
    }
#pragma unroll
    for (int b = 0; b < IN_DIM; b++) {
        float r0 = acc0[b], r1 = acc1[b], r2 = acc2[b];
#pragma unroll
        for (int s = 32; s > 0; s >>= 1) {
            r0 += __shfl_down(r0, s);
            r1 += __shfl_down(r1, s);
            r2 += __shfl_down(r2, s);
        }
        acc0[b] = r0; acc1[b] = r1; acc2[b] = r2;
    }
    if ((threadIdx.x & 63) == 0) {
        float* d0 = S2 + a0 * IN_DIM;
        float* d1 = S2 + a1 * IN_DIM;
        float* d2 = (a2 < IN_DIM) ? (S2 + a2 * IN_DIM) : S1;
#pragma unroll
        for (int b = 0; b < IN_DIM; b++) {
            atomicAdd(&d0[b], acc0[b]);
            atomicAdd(&d1[b], acc1[b]);
            atomicAdd(&d2[b], acc2[b]);
        }
    }
}

__global__ void k_stats(const float* __restrict__ S1, const float* __restrict__ S2,
                        const float* __restrict__ agg, float* __restrict__ mean,
                        float* __restrict__ cov, float* __restrict__ agg0c) {
    int t = threadIdx.x;  // 64
    const float invn = 1.0f / (float)N_NODES;
    if (t < IN_DIM) {
        float m = S1[t] * invn;
        mean[t] = m;
        agg0c[t] = agg[t] - m;
    }
    __syncthreads();
    for (int idx = t; idx < IN_DIM * IN_DIM; idx += 64) {
        int a = idx / IN_DIM, b = idx - a * IN_DIM;
        cov[idx] = S2[idx] * invn - mean[a] * mean[b];
    }
}

__global__ void k_prep(const float* __restrict__ gcn_w, const float* __restrict__ gamma,
                       const float* __restrict__ beta, const float* __restrict__ lin_w,
                       const float* __restrict__ cov, const float* __restrict__ agg0c,
                       float* __restrict__ W2, float* __restrict__ dvec,
                       float* __restrict__ out_rsu) {
    __shared__ float scov[IN_DIM * IN_DIM];
    __shared__ float sa0[IN_DIM];
    int tid = threadIdx.x;
    for (int idx = tid; idx < IN_DIM * IN_DIM; idx += blockDim.x) scov[idx] = cov[idx];
    if (tid < IN_DIM) sa0[tid] = agg0c[tid];
    __syncthreads();
    int j = blockIdx.x * blockDim.x + tid;

    float wcol[IN_DIM];
#pragma unroll
    for (int t = 0; t < IN_DIM; t++) wcol[t] = gcn_w[t * HIDDEN + j];

    float var = 0.f;
#pragma unroll
    for (int t = 0; t < IN_DIM; t++) {
        float s = 0.f;
#pragma unroll
        for (int u = 0; u < IN_DIM; u++) s += scov[t * IN_DIM + u] * wcol[u];
        var += wcol[t] * s;
    }
    float aj = gamma[j] * rsqrtf(var + BN_EPS);

    float e0 = 0.f;
#pragma unroll
    for (int t = 0; t < IN_DIM; t++) e0 += sa0[t] * wcol[t];
    out_rsu[j] = e0 * aj + beta[j];

    float lw0 = lin_w[2 * j], lw1 = lin_w[2 * j + 1];
    float bj = beta[j];
    float vals[42];
#pragma unroll
    for (int t = 0; t < IN_DIM; t++) {
        vals[2 * t]     = wcol[t] * aj * lw0;
        vals[2 * t + 1] = wcol[t] * aj * lw1;
    }
    vals[40] = bj * lw0;
    vals[41] = bj * lw1;
#pragma unroll
    for (int q = 0; q < 42; q++) {
        float v = vals[q];
#pragma unroll
        for (int s = 32; s > 0; s >>= 1) v += __shfl_down(v, s);
        if ((tid & 63) == 0) {
            if (q < 40) atomicAdd(&W2[q], v);
            else        atomicAdd(&dvec[q - 40], v);
        }
    }
}

__global__ void k_final(const float* __restrict__ agg, const float* __restrict__ mean,
                        const float* __restrict__ W2, const float* __restrict__ dvec,
                        const float* __restrict__ lin_b, float* __restrict__ out) {
    int i = blockIdx.x * blockDim.x + threadIdx.x;
    if (i >= N_NODES) return;
    float d0 = dvec[0] + lin_b[0];
    float d1 = dvec[1] + lin_b[1];
#pragma unroll
    for (int t = 0; t < IN_DIM; t++) {
        float v = agg[i * IN_DIM + t] - mean[t];
        d0 += v * W2[2 * t];
        d1 += v * W2[2 * t + 1];
    }
    float l0 = fmaxf(d0, 0.f), l1 = fmaxf(d1, 0.f);
    float m = fmaxf(l0, l1);
    float e0 = expf(l0 - m), e1 = expf(l1 - m);
    float inv = 1.f / (e0 + e1);
    out[2 * i]     = e0 * inv;
    out[2 * i + 1] = e1 * inv;
}

// -------- fallback (scatter) kernels, used only if ws_size < WS_NEED --------
__global__ void k_agginit(const float* __restrict__ nf, const float* __restrict__ dinv,
                          float* __restrict__ agg) {
    int t = blockIdx.x * blockDim.x + threadIdx.x;
    if (t < N_NODES * IN_DIM) {
        int i = t / IN_DIM;
        float d = dinv[i];
        agg[t] = nf[t] * d * d;
    }
}

__global__ void k_scatter(const int* __restrict__ ei, const float* __restrict__ nf,
                          const float* __restrict__ dinv, float* __restrict__ agg) {
    int t = blockIdx.x * blockDim.x + threadIdx.x;
    if (t >= N_EDGES * IN_DIM) return;
    int e = t / IN_DIM;
    int f = t - e * IN_DIM;
    int r = ei[e];
    int c = ei[N_EDGES + e];
    float w = dinv[r] * dinv[c];
    atomicAdd(&agg[c * IN_DIM + f], nf[r * IN_DIM + f] * w);
}

extern "C" void kernel_launch(void* const* d_in, const int* in_sizes, int n_in,
                              void* d_out, int out_size, void* d_ws, size_t ws_size,
                              hipStream_t stream) {
    const float* nf    = (const float*)d_in[0];
    const int*   ei    = (const int*)d_in[1];
    const float* gcn_w = (const float*)d_in[2];
    const float* gamma = (const float*)d_in[4];
    const float* beta  = (const float*)d_in[5];
    const float* lin_w = (const float*)d_in[6];
    const float* lin_b = (const float*)d_in[7];
    float* out = (float*)d_out;

    char* ws = (char*)d_ws;
    int*   deg  = (int*)(ws + 0);
    float* dinv = (float*)(ws + 400000);
    float* agg  = (float*)(ws + 800000);
    int*   bh   = (int*)(ws + 8800000);
    int*   bo   = (int*)(ws + 8804000);
    int*   gcur = (int*)(ws + 8808004);
    float* S1   = (float*)(ws + 8812004);
    float* S2   = (float*)(ws + 8812084);
    float* mean = (float*)(ws + 8813684);
    float* cov  = (float*)(ws + 8813764);
    float* a0c  = (float*)(ws + 8815364);
    float* W2   = (float*)(ws + 8815444);
    float* dvec = (float*)(ws + 8815604);
    int2*  rec  = (int2*)(ws + 8815616);

    hipMemsetAsync(deg, 0, 400000, stream);
    hipMemsetAsync(S1, 0, 3608, stream);

    k_deg<<<(N_EDGES + 255) / 256, 256, 0, stream>>>(ei, deg);
    k_dinv<<<(N_NODES + 255) / 256, 256, 0, stream>>>(deg, dinv);

    if (ws_size >= WS_NEED) {
        k_bh<<<NB, 128, 0, stream>>>(deg, bh);
        k_scan_bo<<<1, 256, 0, stream>>>(bh, bo, gcur);
        k_bin<<<BIN_NWG, 256, 0, stream>>>(ei, gcur, rec);
        k_agg<<<NB, 256, 0, stream>>>(rec, bo, nf, dinv, agg);
    } else {
        k_agginit<<<(N_NODES * IN_DIM + 255) / 256, 256, 0, stream>>>(nf, dinv, agg);
        k_scatter<<<(N_EDGES * IN_DIM + 255) / 256, 256, 0, stream>>>(ei, nf, dinv, agg);
    }

    dim3 gm(32, 7);
    k_moments3<<<gm, 256, 0, stream>>>(agg, S1, S2);
    k_stats<<<1, 64, 0, stream>>>(S1, S2, agg, mean, cov, a0c);
    k_prep<<<HIDDEN / 256, 256, 0, stream>>>(gcn_w, gamma, beta, lin_w, cov, a0c, W2,
                                             dvec, out + 2 * N_NODES);
    k_final<<<(N_NODES + 255) / 256, 256, 0, stream>>>(agg, mean, W2, dvec, lin_b, out);
}